// Round 21
// baseline (281.918 us; speedup 1.0000x reference)
//
#include <hip/hip_runtime.h>

#define Bdim 2
#define Tdim 2048
#define Cdim 2048
#define Hn 16
#define Dh 128
#define NKB 16    // Cdim/128 k-blocks per row
#define LDQK 4096 // row stride of fused q|k output planes

typedef float f32x4 __attribute__((ext_vector_type(4)));
typedef float f32x16 __attribute__((ext_vector_type(16)));
typedef int   i32x8 __attribute__((ext_vector_type(8)));
typedef short s16x4 __attribute__((ext_vector_type(4)));
typedef _Float16 f16x8 __attribute__((ext_vector_type(8)));

#define SCALE1 0x7F7F7F7F   // e8m0 = 1.0 in all 4 bytes
#define BF8FMT 1            // f8f6f4 format code: 1 = E5M2 (bf8)

// async global->LDS, 16B per lane; dest MUST be uniform + lane*16 (m104)
#define GL16(g, l) __builtin_amdgcn_global_load_lds( \
    (const __attribute__((address_space(1))) unsigned int*)(g), \
    (__attribute__((address_space(3))) unsigned int*)(l), 16, 0, 0)

// ---------- numerics helpers ----------

// fp32 -> e5m2 BYTE (RNE, subnormals; matches ml_dtypes rounding)
__device__ __forceinline__ unsigned char q8_byte(float x) {
    unsigned int u = __float_as_uint(x);
    unsigned int sb = (u >> 24) & 0x80u;
    float ax = __uint_as_float(u & 0x7fffffffu);
    unsigned int byte;
    if (ax < 6.103515625e-05f) {              // subnormal grid 2^-16
        byte = (unsigned int)rintf(ax * 65536.0f);
    } else if (ax >= 61440.0f) {
        byte = 0x7Cu;                          // inf (unreachable for our operands)
    } else {
        unsigned int m = __float_as_uint(ax);
        unsigned int rem  = m & 0x001FFFFFu;
        unsigned int keep = m & 0xFFE00000u;
        unsigned int lsb  = (m >> 21) & 1u;
        if (rem > 0x00100000u || (rem == 0x00100000u && lsb)) keep += 0x00200000u;
        unsigned int e = (keep >> 23) & 0xFFu;
        byte = ((e - 112u) << 2) | ((keep >> 21) & 3u);
    }
    return (unsigned char)(byte | sb);
}

__device__ __forceinline__ unsigned short f2h(float f) {
    _Float16 h = (_Float16)f;
    return __builtin_bit_cast(unsigned short, h);
}
__device__ __forceinline__ float exp2_fast(float x) {
    float r; asm volatile("v_exp_f32 %0, %1" : "=v"(r) : "v"(x)); return r;
}

// ---------- fused quant: blocks [0,16384) = weights wq|wk|wv|wo; rest = act ----------
__global__ __launch_bounds__(256) void quant_all_k(const float* __restrict__ x,
                                                   const float* __restrict__ wq,
                                                   const float* __restrict__ wk,
                                                   const float* __restrict__ wv,
                                                   const float* __restrict__ wo,
                                                   unsigned char* __restrict__ xq,
                                                   float* __restrict__ Sx,
                                                   unsigned char* __restrict__ wout) {
    int bx = blockIdx.x;
    if (bx < 16384) {
        int i = (bx * 256 + threadIdx.x) * 4;   // over 16M
        int sel = i >> 22, j = i & ((1 << 22) - 1);
        const float* src = (sel == 0) ? wq : (sel == 1) ? wk : (sel == 2) ? wv : wo;
        float4 t = *(const float4*)(src + j);
        uchar4 o4;
        o4.x = q8_byte(t.x); o4.y = q8_byte(t.y); o4.z = q8_byte(t.z); o4.w = q8_byte(t.w);
        *(uchar4*)(wout + i) = o4;
    } else {
        int wid = (int)(((unsigned)(bx - 16384) * 256u + threadIdx.x) >> 6);
        int lane = threadIdx.x & 63;
        const float* p = x + (size_t)wid * 128;
        float a = p[lane], b = p[lane + 64];
        float m = fmaxf(fabsf(a), fabsf(b));
#pragma unroll
        for (int o = 32; o; o >>= 1) m = fmaxf(m, __shfl_xor(m, o));
        float s = fmaxf(m / 57344.0f, 1e-12f);
        unsigned char* qp = xq + (size_t)wid * 128;
        qp[lane]      = q8_byte(a / s);
        qp[lane + 64] = q8_byte(b / s);
        if (lane == 0) Sx[wid] = s;
    }
}

// ---------- fused QKV GEMM: 128x128, MX 32x32x64 bf8, 2-phase dbuf (GL16 chunk-major) ----------
// LDS layout: slot s holds global (row = s&127, kchunk16B = s>>7); dest = base + s*16 (linear).
// 1-D grid 1536: xcd = bid&7 owns bn panels [xcd*6, xcd*6+6)
__global__ __launch_bounds__(256, 3) void gemm_qkv_k(const unsigned char* __restrict__ Aq,
                                                     const float* __restrict__ Sa,
                                                     const unsigned char* __restrict__ Bq,
                                                     const float* __restrict__ sq,
                                                     const float* __restrict__ sk,
                                                     const float* __restrict__ sv,
                                                     unsigned short* __restrict__ OQK,
                                                     unsigned short* __restrict__ vt) {
    const int K = Cdim;
    __shared__ unsigned char As[2][8192];
    __shared__ unsigned char Bs[2][8192];
    __shared__ float SaR[128 * NKB];   // ratio s_{kb-1}/s_kb (kb==0 -> 1)
    __shared__ float SaF[128];         // s_{NKB-1} per row
    int tid = threadIdx.x;
    int lane = tid & 63, wid = tid >> 6;
    int wr = wid >> 1, wc = wid & 1;
    int bid = blockIdx.x;
    int xcd = bid & 7, ii = bid >> 3;            // ii: 0..191
    int bn = (xcd * 6 + (ii % 6)) * 128;
    int bm = (ii / 6) * 128;

    f32x16 acc[2][2];
#pragma unroll
    for (int i = 0; i < 2; ++i)
#pragma unroll
        for (int j = 0; j < 2; ++j)
#pragma unroll
            for (int e = 0; e < 16; ++e) acc[i][j][e] = 0.f;

    const int lr = lane & 31;
    const int hi = lane >> 5;

    for (int i = tid; i < 128 * NKB; i += 256) {
        int row = i >> 4, kb = i & 15;
        float sc = Sa[(size_t)(bm + row) * NKB + kb];
        SaR[i] = (kb == 0) ? 1.0f : (Sa[(size_t)(bm + row) * NKB + kb - 1] / sc);
    }
    if (tid < 128) SaF[tid] = Sa[(size_t)(bm + tid) * NKB + (NKB - 1)];

#define STAGE_Q(buf, stp) do { \
        int k0s = (stp) << 6; \
        _Pragma("unroll") \
        for (int j = 0; j < 2; ++j) { \
            int s = tid + j * 256; \
            int row = s & 127, q = s >> 7; \
            GL16(Aq + (size_t)(bm + row) * K + k0s + q * 16, As[buf] + s * 16); \
            GL16(Bq + (size_t)(bn + row) * K + k0s + q * 16, Bs[buf] + s * 16); \
        } \
    } while (0)

    STAGE_Q(0, 0);
    __syncthreads();   // drains vmcnt: prologue stage + SaR visible

    const int nstep = K >> 6;   // 32 steps of BK=64
    for (int step = 0; step < nstep; ++step) {
        int cur = step & 1;
        if (step + 1 < nstep) STAGE_Q(cur ^ 1, step + 1);   // issue early, hide under MFMA
        if (step && !(step & 1)) {      // entering k-block kb: rescale acc
            int kb = step >> 1;
#pragma unroll
            for (int m = 0; m < 2; ++m)
#pragma unroll
                for (int reg = 0; reg < 16; ++reg) {
                    int rl = wr * 64 + m * 32 + (reg & 3) + 8 * (reg >> 2) + 4 * hi;
                    float rat = SaR[rl * NKB + kb];
                    acc[m][0][reg] *= rat;
                    acc[m][1][reg] *= rat;
                }
        }
        i32x8 af[2], bf[2];
#pragma unroll
        for (int m = 0; m < 2; ++m) {
            int rowa = wr * 64 + m * 32 + lr;
            int rowb = wc * 64 + m * 32 + lr;
            const unsigned char* ab = As[cur] + (size_t)(hi * 2 * 128 + rowa) * 16;
            const unsigned char* bb = Bs[cur] + (size_t)(hi * 2 * 128 + rowb) * 16;
            int4 va0 = *(const int4*)(const void*)(ab);
            int4 va1 = *(const int4*)(const void*)(ab + 2048);
            int4 vb0 = *(const int4*)(const void*)(bb);
            int4 vb1 = *(const int4*)(const void*)(bb + 2048);
            af[m][0] = va0.x; af[m][1] = va0.y; af[m][2] = va0.z; af[m][3] = va0.w;
            af[m][4] = va1.x; af[m][5] = va1.y; af[m][6] = va1.z; af[m][7] = va1.w;
            bf[m][0] = vb0.x; bf[m][1] = vb0.y; bf[m][2] = vb0.z; bf[m][3] = vb0.w;
            bf[m][4] = vb1.x; bf[m][5] = vb1.y; bf[m][6] = vb1.z; bf[m][7] = vb1.w;
        }
#pragma unroll
        for (int m = 0; m < 2; ++m)
#pragma unroll
            for (int n = 0; n < 2; ++n)
                acc[m][n] = __builtin_amdgcn_mfma_scale_f32_32x32x64_f8f6f4(
                    af[m], bf[n], acc[m][n], BF8FMT, BF8FMT, 0, SCALE1, 0, SCALE1);
        __syncthreads();   // vmcnt(0)+lgkmcnt(0) drain: next buf landed, reads of cur done
    }
#undef STAGE_Q

    int type = bn >> 11;                               // 0:q 1:k 2:v
    const float* Sb = (type == 0) ? sq : (type == 1) ? sk : sv;
    float sb = Sb[(bn & 2047) >> 7];
    // fold attention score scale (1/sqrt(D) * log2e) into the Q plane
    if (type == 0) sb *= 0.088388347648318447f * 1.4426950408889634f;

    if (type < 2) {
#pragma unroll
        for (int m = 0; m < 2; ++m)
#pragma unroll
            for (int n = 0; n < 2; ++n)
#pragma unroll
                for (int reg = 0; reg < 16; ++reg) {
                    int rl = wr * 64 + m * 32 + (reg & 3) + 8 * (reg >> 2) + 4 * hi;
                    int col = bn + wc * 64 + n * 32 + lr;
                    OQK[(size_t)(bm + rl) * LDQK + col] = f2h(acc[m][n][reg] * SaF[rl] * sb);
                }
    } else {
        int hh = (bn - 4096) >> 7;
        int bb = bm >> 11;
        int tb = (bm & 2047) + wr * 64;
        size_t hbase = (((size_t)bb * Hn + hh) * Dh) * Tdim;
#pragma unroll
        for (int n = 0; n < 2; ++n) {
            int d = wc * 64 + n * 32 + lr;
#pragma unroll
            for (int m = 0; m < 2; ++m)
#pragma unroll
                for (int g = 0; g < 4; ++g) {
                    s16x4 h4;
#pragma unroll
                    for (int r = 0; r < 4; ++r) {
                        int rl = wr * 64 + m * 32 + r + 8 * g + 4 * hi;
                        h4[r] = (short)f2h(acc[m][n][g * 4 + r] * SaF[rl] * sb);
                    }
                    *(s16x4*)(void*)(vt + hbase + (size_t)d * Tdim + tb + m * 32 + 8 * g + 4 * hi) = h4;
                }
        }
    }
}

// ---------- final GEMM: 64x128 tile, MX bf8, 2-phase dbuf (GL16 chunk-major) ----------
__global__ __launch_bounds__(256, 4) void gemm_k(const unsigned char* __restrict__ Aq,
                                                 const float* __restrict__ Sa,
                                                 const unsigned char* __restrict__ Bq,
                                                 const float* __restrict__ Sb,
                                                 float* __restrict__ Of,
                                                 int M, int N, int K) {
    __shared__ unsigned char As[2][4096];
    __shared__ unsigned char Bs[2][8192];
    __shared__ float SaR[64 * NKB];
    __shared__ float SaF[64];
    int tid = threadIdx.x;
    int lane = tid & 63, wid = tid >> 6;
    int wr = wid >> 1, wc = wid & 1;
    int bid = blockIdx.x;
    int xcd = bid & 7, ii = bid >> 3;            // ii: 0..127
    int bn = (xcd * 2 + (ii & 1)) * 128;
    int bm = (ii >> 1) * 64;

    f32x16 acc[2];
#pragma unroll
    for (int j = 0; j < 2; ++j)
#pragma unroll
        for (int e = 0; e < 16; ++e) acc[j][e] = 0.f;

    const int lr = lane & 31;
    const int hi = lane >> 5;

    for (int i = tid; i < 64 * NKB; i += 256) {
        int row = i >> 4, kb = i & 15;
        float sc = Sa[(size_t)(bm + row) * NKB + kb];
        SaR[i] = (kb == 0) ? 1.0f : (Sa[(size_t)(bm + row) * NKB + kb - 1] / sc);
    }
    if (tid < 64) SaF[tid] = Sa[(size_t)(bm + tid) * NKB + (NKB - 1)];

#define STAGE_F(buf, stp) do { \
        int k0s = (stp) << 6; \
        { \
            int rowA = tid & 63, qA = tid >> 6; \
            GL16(Aq + (size_t)(bm + rowA) * K + k0s + qA * 16, As[buf] + tid * 16); \
        } \
        _Pragma("unroll") \
        for (int j = 0; j < 2; ++j) { \
            int s = tid + j * 256; \
            int row = s & 127, q = s >> 7; \
            GL16(Bq + (size_t)(bn + row) * K + k0s + q * 16, Bs[buf] + s * 16); \
        } \
    } while (0)

    STAGE_F(0, 0);
    __syncthreads();

    const int nstep = K >> 6;
    for (int step = 0; step < nstep; ++step) {
        int cur = step & 1;
        if (step + 1 < nstep) STAGE_F(cur ^ 1, step + 1);
        if (step && !(step & 1)) {
            int kb = step >> 1;
#pragma unroll
            for (int reg = 0; reg < 16; ++reg) {
                int rl = wr * 32 + (reg & 3) + 8 * (reg >> 2) + 4 * hi;
                float rat = SaR[rl * NKB + kb];
                acc[0][reg] *= rat;
                acc[1][reg] *= rat;
            }
        }
        i32x8 af, bf[2];
        {
            int rowa = wr * 32 + lr;
            const unsigned char* ab = As[cur] + (size_t)(hi * 2 * 64 + rowa) * 16;
            int4 va0 = *(const int4*)(const void*)(ab);
            int4 va1 = *(const int4*)(const void*)(ab + 1024);
            af[0] = va0.x; af[1] = va0.y; af[2] = va0.z; af[3] = va0.w;
            af[4] = va1.x; af[5] = va1.y; af[6] = va1.z; af[7] = va1.w;
#pragma unroll
            for (int n = 0; n < 2; ++n) {
                int rowb = wc * 64 + n * 32 + lr;
                const unsigned char* bb = Bs[cur] + (size_t)(hi * 2 * 128 + rowb) * 16;
                int4 vb0 = *(const int4*)(const void*)(bb);
                int4 vb1 = *(const int4*)(const void*)(bb + 2048);
                bf[n][0] = vb0.x; bf[n][1] = vb0.y; bf[n][2] = vb0.z; bf[n][3] = vb0.w;
                bf[n][4] = vb1.x; bf[n][5] = vb1.y; bf[n][6] = vb1.z; bf[n][7] = vb1.w;
            }
        }
#pragma unroll
        for (int n = 0; n < 2; ++n)
            acc[n] = __builtin_amdgcn_mfma_scale_f32_32x32x64_f8f6f4(
                af, bf[n], acc[n], BF8FMT, BF8FMT, 0, SCALE1, 0, SCALE1);
        __syncthreads();
    }
#undef STAGE_F

    float sb = Sb[bn >> 7];
#pragma unroll
    for (int n = 0; n < 2; ++n)
#pragma unroll
        for (int reg = 0; reg < 16; ++reg) {
            int rl = wr * 32 + (reg & 3) + 8 * (reg >> 2) + 4 * hi;
            int col = bn + wc * 64 + n * 32 + lr;
            Of[(size_t)(bm + rl) * N + col] = acc[n][reg] * SaF[rl] * sb;
        }
}

// ---------- flash attention: swapped QK^T (lane-local softmax), fp16, QB=64 ----------
#define QB 64
#define KB 32
#define PLD32 20   // Ps row stride in u32 (80B, 16B-aligned)

__global__ __launch_bounds__(256, 4) void attn_k(const unsigned short* __restrict__ Qp_,
                                                 const unsigned short* __restrict__ Kp_,
                                                 const unsigned short* __restrict__ Vp_,
                                                 unsigned char* __restrict__ ctxq,
                                                 float* __restrict__ Sc) {
    __shared__ unsigned short Kb[2][4096];
    __shared__ unsigned short Vb[2][4096];
    __shared__ unsigned int Ps[4][16 * PLD32];

    int tid = threadIdx.x, lane = tid & 63, wid = tid >> 6;
    int g = blockIdx.x;
    int h = g & 15, b = (g >> 4) & 1;
    int idx = g >> 5;
    int jj = idx >> 3, rr8 = idx & 7;
    int qt = (jj << 3) | ((jj & 1) ? (7 - rr8) : rr8);   // snake: per-CU work uniform

    const size_t qkbase = (size_t)b * Tdim * LDQK + (size_t)h * Dh;
    const size_t cqbase = (size_t)b * Tdim * Cdim + (size_t)h * Dh;
    const size_t vbase  = ((size_t)b * Hn + h) * (size_t)Dh * Tdim;
    const unsigned short* Qp = Qp_ + qkbase;
    const unsigned short* Kp = Kp_ + qkbase;
    const unsigned short* Vp = Vp_ + vbase;

    int cl = lane & 15, gq = lane >> 4;
    int fk = gq * 8, rb4 = gq * 4;

    int qrow_lo = qt * QB + wid * 16;
    int myq = qrow_lo + cl;
    int qmax_w = qrow_lo + 15;

    f16x8 qf[4];   // Q pre-scaled by (1/sqrt(D))*log2e at gemm_qkv epilogue
#pragma unroll
    for (int c = 0; c < 4; ++c)
        qf[c] = *(const f16x8*)(const void*)(Qp + (size_t)myq * LDQK + c * 32 + fk);

    f32x4 acc[8];
#pragma unroll
    for (int n = 0; n < 8; ++n) acc[n] = (f32x4){0.f, 0.f, 0.f, 0.f};
    float mrun = -__builtin_inff(), lrun = 0.f;

#define STAGE_T(buf, j0s) do { \
        _Pragma("unroll") \
        for (int i2 = 0; i2 < 2; ++i2) { \
            int s = i2 * 256 + tid; \
            int r_ = s >> 4, ch_ = (s & 15) ^ (r_ & 7); \
            GL16(Kp + (size_t)((j0s) + r_) * LDQK + ch_ * 8, Kb[buf] + s * 8); \
            int d_ = s >> 2, cv_ = (s & 3) ^ ((d_ >> 1) & 3); \
            GL16(Vp + (size_t)d_ * Tdim + (j0s) + cv_ * 8, Vb[buf] + s * 8); \
        } \
    } while (0)

    int ntile = 2 * qt + 2;
    int cur = 0;
    STAGE_T(0, 0);
    __syncthreads();

    for (int t = 0; t < ntile; ++t) {
        int j0 = t * KB;
        if (t + 1 < ntile) STAGE_T(cur ^ 1, j0 + KB);
        if (j0 <= qmax_w) {
            f32x4 sT[2];
#pragma unroll
            for (int st = 0; st < 2; ++st) {
                int rr = st * 16 + cl;
                f32x4 sa = (f32x4){0.f, 0.f, 0.f, 0.f};
#pragma unroll
                for (int c = 0; c < 4; ++c) {
                    int slot = rr * 16 + ((c * 4 + gq) ^ (rr & 7));
                    f16x8 kf = *(const f16x8*)(const void*)(Kb[cur] + slot * 8);
                    sa = __builtin_amdgcn_mfma_f32_16x16x32_f16(kf, qf[c], sa, 0, 0, 0);
                }
                sT[st] = sa;
            }
            // causal mask only on tiles that can cross the diagonal (wave-uniform)
            if (j0 + KB - 1 > qrow_lo) {
#pragma unroll
                for (int st = 0; st < 2; ++st)
#pragma unroll
                    for (int r = 0; r < 4; ++r) {
                        int key = j0 + st * 16 + rb4 + r;
                        if (key > myq) sT[st][r] = -__builtin_inff();
                    }
            }
            float smax = sT[0][0];
#pragma unroll
            for (int r = 1; r < 4; ++r) smax = fmaxf(smax, sT[0][r]);
#pragma unroll
            for (int r = 0; r < 4; ++r) smax = fmaxf(smax, sT[1][r]);
            smax = fmaxf(smax, __shfl_xor(smax, 16));
            smax = fmaxf(smax, __shfl_xor(smax, 32));
            bool need = smax > mrun + 8.f;
            if (__any(need)) {
                float mn = fmaxf(mrun, smax);
                float corr = exp2_fast(mrun - mn);
                mrun = mn;
                lrun *= corr;
#pragma unroll
                for (int r = 0; r < 4; ++r) {
                    float ca = __shfl(corr, rb4 + r);
#pragma unroll
                    for (int n = 0; n < 8; ++n) acc[n][r] *= ca;
                }
            }
            float p[2][4];
            float rs = 0.f;
#pragma unroll
            for (int st = 0; st < 2; ++st)
#pragma unroll
                for (int r = 0; r < 4; ++r) {
                    p[st][r] = exp2_fast(sT[st][r] - mrun);
                    rs += p[st][r];
                }
            rs += __shfl_xor(rs, 16);
            rs += __shfl_xor(rs, 32);
            lrun += rs;
            unsigned int* ps = &Ps[wid][0];
#pragma unroll
            for (int st = 0; st < 2; ++st) {
                unsigned int v0 = __builtin_bit_cast(unsigned int,
                    __builtin_amdgcn_cvt_pkrtz(p[st][0], p[st][1]));
                unsigned int v1 = __builtin_bit_cast(unsigned int,
                    __builtin_amdgcn_cvt_pkrtz(p[st][2], p[st][3]));
                ps[cl * PLD32 + st * 8 + gq * 2]     = v0;
                ps[cl * PLD32 + st * 8 + gq * 2 + 1] = v1;
            }
            f16x8 pf = *(const f16x8*)(const void*)(ps + cl * PLD32 + gq * 4);
#pragma unroll
            for (int n = 0; n < 8; ++n) {
                int d = n * 16 + cl;
                int slot = d * 4 + (gq ^ ((d >> 1) & 3));
                f16x8 vf = *(const f16x8*)(const void*)(Vb[cur] + slot * 8);
                acc[n] = __builtin_amdgcn_mfma_f32_16x16x32_f16(pf, vf, acc[n], 0, 0, 0);
            }
        }
        __syncthreads();
        cur ^= 1;
    }
#undef STAGE_T
    unsigned char* cq = ctxq + cqbase;
#pragma unroll
    for (int r = 0; r < 4; ++r) {
        int trow = qrow_lo + rb4 + r;
        float inv = 1.0f / __shfl(lrun, rb4 + r);
        float vals[8];
        float am = 0.f;
#pragma unroll
        for (int n = 0; n < 8; ++n) {
            vals[n] = acc[n][r] * inv;
            am = fmaxf(am, fabsf(vals[n]));
        }
#pragma unroll
        for (int o = 8; o; o >>= 1) am = fmaxf(am, __shfl_xor(am, o));
        float s = fmaxf(am / 57344.0f, 1e-12f);
#pragma unroll
        for (int n = 0; n < 8; ++n)
            cq[(size_t)trow * Cdim + n * 16 + cl] = q8_byte(vals[n] / s);
        if (cl == 0) Sc[((size_t)b * Tdim + trow) * NKB + h] = s;
    }
}

// ---------- launch ----------
extern "C" void kernel_launch(void* const* d_in, const int* in_sizes, int n_in,
                              void* d_out, int out_size, void* d_ws, size_t ws_size,
                              hipStream_t stream) {
    const float* x  = (const float*)d_in[0];
    const float* wq = (const float*)d_in[2];
    const float* wk = (const float*)d_in[3];
    const float* wv = (const float*)d_in[4];
    const float* wo = (const float*)d_in[5];
    const float* sq = (const float*)d_in[6];
    const float* sk = (const float*)d_in[7];
    const float* sv = (const float*)d_in[8];
    const float* so = (const float*)d_in[9];

    const size_t MB = 1ull << 20;
    char* ws = (char*)d_ws;
    unsigned char*  xq   = (unsigned char*)(ws);                           // 8MB
    float*          Sx   = (float*)(ws + 8 * MB);                          // 256KB
    float*          Scx  = (float*)(ws + (8 * MB + 256 * 1024));           // 256KB
    unsigned char*  wdq4 = (unsigned char*)(ws + (8 * MB + 512 * 1024));   // 16MB (q|k|v|o)
    unsigned short* OQK  = (unsigned short*)(ws + (24 * MB + 512 * 1024)); // 32MB fp16 q|k
    unsigned short* vt   = (unsigned short*)(ws + (56 * MB + 512 * 1024)); // 16MB fp16 V^T
    unsigned char*  cq   = (unsigned char*)(ws + (72 * MB + 512 * 1024));  // 8MB

    const int Mr = Bdim * Tdim;

    quant_all_k<<<32768, 256, 0, stream>>>(x, wq, wk, wv, wo, xq, Sx, wdq4);

    gemm_qkv_k<<<1536, 256, 0, stream>>>(xq, Sx, wdq4, sq, sk, sv, OQK, vt);

    attn_k<<<1024, 256, 0, stream>>>(OQK, OQK + 2048, vt, cq, Scx);

    gemm_k<<<1024, 256, 0, stream>>>(cq, Scx, wdq4 + (6144ull * 2048), so,
                                     (float*)d_out, Mr, Cdim, Cdim);
}

// Round 22
// 229.476 us; speedup vs baseline: 1.2285x; 1.2285x over previous
//
#include <hip/hip_runtime.h>

#define Bdim 2
#define Tdim 2048
#define Cdim 2048
#define Hn 16
#define Dh 128
#define NKB 16    // Cdim/128 k-blocks per row
#define LDQK 4096 // row stride of fused q|k output planes

typedef float f32x4 __attribute__((ext_vector_type(4)));
typedef float f32x16 __attribute__((ext_vector_type(16)));
typedef int   i32x8 __attribute__((ext_vector_type(8)));
typedef short s16x4 __attribute__((ext_vector_type(4)));
typedef _Float16 f16x8 __attribute__((ext_vector_type(8)));

#define SCALE1 0x7F7F7F7F   // e8m0 = 1.0 in all 4 bytes
#define BF8FMT 1            // f8f6f4 format code: 1 = E5M2 (bf8)

// async global->LDS, 16B per lane, linear dest (base + lane*16)
#define GL16(g, l) __builtin_amdgcn_global_load_lds( \
    (const __attribute__((address_space(1))) unsigned int*)(g), \
    (__attribute__((address_space(3))) unsigned int*)(l), 16, 0, 0)

// ---------- numerics helpers ----------

// fp32 -> e5m2 BYTE (RNE, subnormals; matches ml_dtypes rounding)
__device__ __forceinline__ unsigned char q8_byte(float x) {
    unsigned int u = __float_as_uint(x);
    unsigned int sb = (u >> 24) & 0x80u;
    float ax = __uint_as_float(u & 0x7fffffffu);
    unsigned int byte;
    if (ax < 6.103515625e-05f) {              // subnormal grid 2^-16
        byte = (unsigned int)rintf(ax * 65536.0f);
    } else if (ax >= 61440.0f) {
        byte = 0x7Cu;                          // inf (unreachable for our operands)
    } else {
        unsigned int m = __float_as_uint(ax);
        unsigned int rem  = m & 0x001FFFFFu;
        unsigned int keep = m & 0xFFE00000u;
        unsigned int lsb  = (m >> 21) & 1u;
        if (rem > 0x00100000u || (rem == 0x00100000u && lsb)) keep += 0x00200000u;
        unsigned int e = (keep >> 23) & 0xFFu;
        byte = ((e - 112u) << 2) | ((keep >> 21) & 3u);
    }
    return (unsigned char)(byte | sb);
}

__device__ __forceinline__ unsigned short f2h(float f) {
    _Float16 h = (_Float16)f;
    return __builtin_bit_cast(unsigned short, h);
}
__device__ __forceinline__ float exp2_fast(float x) {
    float r; asm volatile("v_exp_f32 %0, %1" : "=v"(r) : "v"(x)); return r;
}

// ---------- fused quant: blocks [0,16384) = weights wq|wk|wv|wo; rest = act ----------
__global__ __launch_bounds__(256) void quant_all_k(const float* __restrict__ x,
                                                   const float* __restrict__ wq,
                                                   const float* __restrict__ wk,
                                                   const float* __restrict__ wv,
                                                   const float* __restrict__ wo,
                                                   unsigned char* __restrict__ xq,
                                                   float* __restrict__ Sx,
                                                   unsigned char* __restrict__ wout) {
    int bx = blockIdx.x;
    if (bx < 16384) {
        int i = (bx * 256 + threadIdx.x) * 4;   // over 16M
        int sel = i >> 22, j = i & ((1 << 22) - 1);
        const float* src = (sel == 0) ? wq : (sel == 1) ? wk : (sel == 2) ? wv : wo;
        float4 t = *(const float4*)(src + j);
        uchar4 o4;
        o4.x = q8_byte(t.x); o4.y = q8_byte(t.y); o4.z = q8_byte(t.z); o4.w = q8_byte(t.w);
        *(uchar4*)(wout + i) = o4;
    } else {
        int wid = (int)(((unsigned)(bx - 16384) * 256u + threadIdx.x) >> 6);
        int lane = threadIdx.x & 63;
        const float* p = x + (size_t)wid * 128;
        float a = p[lane], b = p[lane + 64];
        float m = fmaxf(fabsf(a), fabsf(b));
#pragma unroll
        for (int o = 32; o; o >>= 1) m = fmaxf(m, __shfl_xor(m, o));
        float s = fmaxf(m / 57344.0f, 1e-12f);
        unsigned char* qp = xq + (size_t)wid * 128;
        qp[lane]      = q8_byte(a / s);
        qp[lane + 64] = q8_byte(b / s);
        if (lane == 0) Sx[wid] = s;
    }
}

#define LB 80   // LDS row stride in bytes (64B row + 16B pad; 16B-aligned rows)

// ---------- fused QKV GEMM: 128x128, MX 32x32x64 bf8 MFMA (unit scales) + running rescale ----------
__global__ __launch_bounds__(256, 4) void gemm_qkv_k(const unsigned char* __restrict__ Aq,
                                                     const float* __restrict__ Sa,
                                                     const unsigned char* __restrict__ Bq,
                                                     const float* __restrict__ sq,
                                                     const float* __restrict__ sk,
                                                     const float* __restrict__ sv,
                                                     unsigned short* __restrict__ OQK,
                                                     unsigned short* __restrict__ vt) {
    const int K = Cdim;
    __shared__ unsigned char As[128 * LB];
    __shared__ unsigned char Bs[128 * LB];
    __shared__ float SaR[128 * NKB];   // ratio s_{kb-1}/s_kb (kb==0 -> 1)
    __shared__ float SaF[128];         // s_{NKB-1} per row
    int tid = threadIdx.x;
    int lane = tid & 63, wid = tid >> 6;
    int wr = wid >> 1, wc = wid & 1;
    int bm = blockIdx.y * 128, bn = blockIdx.x * 128;

    f32x16 acc[2][2];
#pragma unroll
    for (int i = 0; i < 2; ++i)
#pragma unroll
        for (int j = 0; j < 2; ++j)
#pragma unroll
            for (int e = 0; e < 16; ++e) acc[i][j][e] = 0.f;

    const int lr = lane & 31;
    const int hi = lane >> 5;

    for (int i = tid; i < 128 * NKB; i += 256) {
        int row = i >> 4, kb = i & 15;
        float sc = Sa[(size_t)(bm + row) * NKB + kb];
        SaR[i] = (kb == 0) ? 1.0f : (Sa[(size_t)(bm + row) * NKB + kb - 1] / sc);
    }
    if (tid < 128) SaF[tid] = Sa[(size_t)(bm + tid) * NKB + (NKB - 1)];

    const int nstep = K >> 6;   // 32 steps of BK=64
    for (int step = 0; step < nstep; ++step) {
        int k0 = step << 6;
        __syncthreads();
#pragma unroll
        for (int j = 0; j < 2; ++j) {
            int idx = tid + j * 256;
            int row = idx >> 2, ch = (idx & 3) * 16;
            *(int4*)(void*)(As + row * LB + ch) =
                *(const int4*)(const void*)(Aq + (size_t)(bm + row) * K + k0 + ch);
            *(int4*)(void*)(Bs + row * LB + ch) =
                *(const int4*)(const void*)(Bq + (size_t)(bn + row) * K + k0 + ch);
        }
        __syncthreads();
        if (step && !(step & 1)) {      // entering k-block kb: rescale acc
            int kb = step >> 1;
#pragma unroll
            for (int m = 0; m < 2; ++m)
#pragma unroll
                for (int reg = 0; reg < 16; ++reg) {
                    int rl = wr * 64 + m * 32 + (reg & 3) + 8 * (reg >> 2) + 4 * hi;
                    float rat = SaR[rl * NKB + kb];
                    acc[m][0][reg] *= rat;
                    acc[m][1][reg] *= rat;
                }
        }
        i32x8 af[2], bf[2];
#pragma unroll
        for (int m = 0; m < 2; ++m) {
            const unsigned char* ab = As + (wr * 64 + m * 32 + lr) * LB + hi * 32;
            const unsigned char* bb = Bs + (wc * 64 + m * 32 + lr) * LB + hi * 32;
            int4 va0 = *(const int4*)(const void*)(ab);
            int4 va1 = *(const int4*)(const void*)(ab + 16);
            int4 vb0 = *(const int4*)(const void*)(bb);
            int4 vb1 = *(const int4*)(const void*)(bb + 16);
            af[m][0] = va0.x; af[m][1] = va0.y; af[m][2] = va0.z; af[m][3] = va0.w;
            af[m][4] = va1.x; af[m][5] = va1.y; af[m][6] = va1.z; af[m][7] = va1.w;
            bf[m][0] = vb0.x; bf[m][1] = vb0.y; bf[m][2] = vb0.z; bf[m][3] = vb0.w;
            bf[m][4] = vb1.x; bf[m][5] = vb1.y; bf[m][6] = vb1.z; bf[m][7] = vb1.w;
        }
#pragma unroll
        for (int m = 0; m < 2; ++m)
#pragma unroll
            for (int n = 0; n < 2; ++n)
                acc[m][n] = __builtin_amdgcn_mfma_scale_f32_32x32x64_f8f6f4(
                    af[m], bf[n], acc[m][n], BF8FMT, BF8FMT, 0, SCALE1, 0, SCALE1);
    }

    int type = bn >> 11;                               // 0:q 1:k 2:v
    const float* Sb = (type == 0) ? sq : (type == 1) ? sk : sv;
    float sb = Sb[(bn & 2047) >> 7];
    // fold attention score scale (1/sqrt(D) * log2e) into the Q plane
    if (type == 0) sb *= 0.088388347648318447f * 1.4426950408889634f;

    if (type < 2) {
#pragma unroll
        for (int m = 0; m < 2; ++m)
#pragma unroll
            for (int n = 0; n < 2; ++n)
#pragma unroll
                for (int reg = 0; reg < 16; ++reg) {
                    int rl = wr * 64 + m * 32 + (reg & 3) + 8 * (reg >> 2) + 4 * hi;
                    int col = bn + wc * 64 + n * 32 + lr;
                    OQK[(size_t)(bm + rl) * LDQK + col] = f2h(acc[m][n][reg] * SaF[rl] * sb);
                }
    } else {
        int hh = (bn - 4096) >> 7;
        int bb = bm >> 11;
        int tb = (bm & 2047) + wr * 64;
        size_t hbase = (((size_t)bb * Hn + hh) * Dh) * Tdim;
#pragma unroll
        for (int n = 0; n < 2; ++n) {
            int d = wc * 64 + n * 32 + lr;
#pragma unroll
            for (int m = 0; m < 2; ++m)
#pragma unroll
                for (int g = 0; g < 4; ++g) {
                    s16x4 h4;
#pragma unroll
                    for (int r = 0; r < 4; ++r) {
                        int rl = wr * 64 + m * 32 + r + 8 * g + 4 * hi;
                        h4[r] = (short)f2h(acc[m][n][g * 4 + r] * SaF[rl] * sb);
                    }
                    *(s16x4*)(void*)(vt + hbase + (size_t)d * Tdim + tb + m * 32 + 8 * g + 4 * hi) = h4;
                }
        }
    }
}

// ---------- final GEMM: 64x128 tile, MX 32x32x64 bf8 (unit scales) + running rescale ----------
__global__ __launch_bounds__(256, 4) void gemm_k(const unsigned char* __restrict__ Aq,
                                                 const float* __restrict__ Sa,
                                                 const unsigned char* __restrict__ Bq,
                                                 const float* __restrict__ Sb,
                                                 float* __restrict__ Of,
                                                 int M, int N, int K) {
    __shared__ unsigned char As[64 * LB];
    __shared__ unsigned char Bs[128 * LB];
    __shared__ float SaR[64 * NKB];
    __shared__ float SaF[64];
    int tid = threadIdx.x;
    int lane = tid & 63, wid = tid >> 6;
    int wr = wid >> 1, wc = wid & 1;      // wr: 32-row slab, wc: 64-col slab
    int bm = blockIdx.y * 64, bn = blockIdx.x * 128;

    f32x16 acc[2];
#pragma unroll
    for (int j = 0; j < 2; ++j)
#pragma unroll
        for (int e = 0; e < 16; ++e) acc[j][e] = 0.f;

    const int lr = lane & 31;
    const int hi = lane >> 5;

    for (int i = tid; i < 64 * NKB; i += 256) {
        int row = i >> 4, kb = i & 15;
        float sc = Sa[(size_t)(bm + row) * NKB + kb];
        SaR[i] = (kb == 0) ? 1.0f : (Sa[(size_t)(bm + row) * NKB + kb - 1] / sc);
    }
    if (tid < 64) SaF[tid] = Sa[(size_t)(bm + tid) * NKB + (NKB - 1)];

    const int nstep = K >> 6;
    for (int step = 0; step < nstep; ++step) {
        int k0 = step << 6;
        __syncthreads();
        {   // stage As: 64 rows x 64B (1 int4/thread); Bs: 128 rows x 64B (2)
            int rowA = tid >> 2, chA = (tid & 3) * 16;
            *(int4*)(void*)(As + rowA * LB + chA) =
                *(const int4*)(const void*)(Aq + (size_t)(bm + rowA) * K + k0 + chA);
#pragma unroll
            for (int j = 0; j < 2; ++j) {
                int idx = tid + j * 256;
                int row = idx >> 2, ch = (idx & 3) * 16;
                *(int4*)(void*)(Bs + row * LB + ch) =
                    *(const int4*)(const void*)(Bq + (size_t)(bn + row) * K + k0 + ch);
            }
        }
        __syncthreads();
        if (step && !(step & 1)) {
            int kb = step >> 1;
#pragma unroll
            for (int reg = 0; reg < 16; ++reg) {
                int rl = wr * 32 + (reg & 3) + 8 * (reg >> 2) + 4 * hi;
                float rat = SaR[rl * NKB + kb];
                acc[0][reg] *= rat;
                acc[1][reg] *= rat;
            }
        }
        i32x8 af, bf[2];
        {
            const unsigned char* ab = As + (wr * 32 + lr) * LB + hi * 32;
            int4 va0 = *(const int4*)(const void*)(ab);
            int4 va1 = *(const int4*)(const void*)(ab + 16);
            af[0] = va0.x; af[1] = va0.y; af[2] = va0.z; af[3] = va0.w;
            af[4] = va1.x; af[5] = va1.y; af[6] = va1.z; af[7] = va1.w;
#pragma unroll
            for (int n = 0; n < 2; ++n) {
                const unsigned char* bb = Bs + (wc * 64 + n * 32 + lr) * LB + hi * 32;
                int4 vb0 = *(const int4*)(const void*)(bb);
                int4 vb1 = *(const int4*)(const void*)(bb + 16);
                bf[n][0] = vb0.x; bf[n][1] = vb0.y; bf[n][2] = vb0.z; bf[n][3] = vb0.w;
                bf[n][4] = vb1.x; bf[n][5] = vb1.y; bf[n][6] = vb1.z; bf[n][7] = vb1.w;
            }
        }
#pragma unroll
        for (int n = 0; n < 2; ++n)
            acc[n] = __builtin_amdgcn_mfma_scale_f32_32x32x64_f8f6f4(
                af, bf[n], acc[n], BF8FMT, BF8FMT, 0, SCALE1, 0, SCALE1);
    }

    float sb = Sb[bn >> 7];
#pragma unroll
    for (int n = 0; n < 2; ++n)
#pragma unroll
        for (int reg = 0; reg < 16; ++reg) {
            int rl = wr * 32 + (reg & 3) + 8 * (reg >> 2) + 4 * hi;
            int col = bn + wc * 64 + n * 32 + lr;
            Of[(size_t)(bm + rl) * N + col] = acc[n][reg] * SaF[rl] * sb;
        }
}

// ---------- flash attention: swapped QK^T (lane-local softmax), fp16, QB=64 ----------
#define QB 64
#define KB 32
#define PLD32 20   // Ps row stride in u32 (80B, 16B-aligned)

__global__ __launch_bounds__(256, 4) void attn_k(const unsigned short* __restrict__ Qp_,
                                                 const unsigned short* __restrict__ Kp_,
                                                 const unsigned short* __restrict__ Vp_,
                                                 unsigned char* __restrict__ ctxq,
                                                 float* __restrict__ Sc) {
    __shared__ unsigned short Kb[2][4096];
    __shared__ unsigned short Vb[2][4096];
    __shared__ unsigned int Ps[4][16 * PLD32];

    int tid = threadIdx.x, lane = tid & 63, wid = tid >> 6;
    int g = blockIdx.x;
    int h = g & 15, b = (g >> 4) & 1;
    int idx = g >> 5;
    int jj = idx >> 3, rr8 = idx & 7;
    int qt = (jj << 3) | ((jj & 1) ? (7 - rr8) : rr8);   // snake: per-CU work uniform

    const size_t qkbase = (size_t)b * Tdim * LDQK + (size_t)h * Dh;
    const size_t cqbase = (size_t)b * Tdim * Cdim + (size_t)h * Dh;
    const size_t vbase  = ((size_t)b * Hn + h) * (size_t)Dh * Tdim;
    const unsigned short* Qp = Qp_ + qkbase;
    const unsigned short* Kp = Kp_ + qkbase;
    const unsigned short* Vp = Vp_ + vbase;

    int cl = lane & 15, gq = lane >> 4;
    int fk = gq * 8, rb4 = gq * 4;

    int qrow_lo = qt * QB + wid * 16;
    int myq = qrow_lo + cl;
    int qmax_w = qrow_lo + 15;

    f16x8 qf[4];   // Q pre-scaled by (1/sqrt(D))*log2e at gemm_qkv epilogue
#pragma unroll
    for (int c = 0; c < 4; ++c)
        qf[c] = *(const f16x8*)(const void*)(Qp + (size_t)myq * LDQK + c * 32 + fk);

    f32x4 acc[8];
#pragma unroll
    for (int n = 0; n < 8; ++n) acc[n] = (f32x4){0.f, 0.f, 0.f, 0.f};
    float mrun = -__builtin_inff(), lrun = 0.f;

#define STAGE_T(buf, j0s) do { \
        _Pragma("unroll") \
        for (int i2 = 0; i2 < 2; ++i2) { \
            int s = i2 * 256 + tid; \
            int r_ = s >> 4, ch_ = (s & 15) ^ (r_ & 7); \
            GL16(Kp + (size_t)((j0s) + r_) * LDQK + ch_ * 8, Kb[buf] + s * 8); \
            int d_ = s >> 2, cv_ = (s & 3) ^ ((d_ >> 1) & 3); \
            GL16(Vp + (size_t)d_ * Tdim + (j0s) + cv_ * 8, Vb[buf] + s * 8); \
        } \
    } while (0)

    int ntile = 2 * qt + 2;
    int cur = 0;
    STAGE_T(0, 0);
    __syncthreads();

    for (int t = 0; t < ntile; ++t) {
        int j0 = t * KB;
        if (t + 1 < ntile) STAGE_T(cur ^ 1, j0 + KB);
        if (j0 <= qmax_w) {
            f32x4 sT[2];
#pragma unroll
            for (int st = 0; st < 2; ++st) {
                int rr = st * 16 + cl;
                f32x4 sa = (f32x4){0.f, 0.f, 0.f, 0.f};
#pragma unroll
                for (int c = 0; c < 4; ++c) {
                    int slot = rr * 16 + ((c * 4 + gq) ^ (rr & 7));
                    f16x8 kf = *(const f16x8*)(const void*)(Kb[cur] + slot * 8);
                    sa = __builtin_amdgcn_mfma_f32_16x16x32_f16(kf, qf[c], sa, 0, 0, 0);
                }
                sT[st] = sa;
            }
            // causal mask only on tiles that can cross the diagonal (wave-uniform)
            if (j0 + KB - 1 > qrow_lo) {
#pragma unroll
                for (int st = 0; st < 2; ++st)
#pragma unroll
                    for (int r = 0; r < 4; ++r) {
                        int key = j0 + st * 16 + rb4 + r;
                        if (key > myq) sT[st][r] = -__builtin_inff();
                    }
            }
            float smax = sT[0][0];
#pragma unroll
            for (int r = 1; r < 4; ++r) smax = fmaxf(smax, sT[0][r]);
#pragma unroll
            for (int r = 0; r < 4; ++r) smax = fmaxf(smax, sT[1][r]);
            smax = fmaxf(smax, __shfl_xor(smax, 16));
            smax = fmaxf(smax, __shfl_xor(smax, 32));
            bool need = smax > mrun + 8.f;
            if (__any(need)) {
                float mn = fmaxf(mrun, smax);
                float corr = exp2_fast(mrun - mn);
                mrun = mn;
                lrun *= corr;
#pragma unroll
                for (int r = 0; r < 4; ++r) {
                    float ca = __shfl(corr, rb4 + r);
#pragma unroll
                    for (int n = 0; n < 8; ++n) acc[n][r] *= ca;
                }
            }
            float p[2][4];
            float rs = 0.f;
#pragma unroll
            for (int st = 0; st < 2; ++st)
#pragma unroll
                for (int r = 0; r < 4; ++r) {
                    p[st][r] = exp2_fast(sT[st][r] - mrun);
                    rs += p[st][r];
                }
            rs += __shfl_xor(rs, 16);
            rs += __shfl_xor(rs, 32);
            lrun += rs;
            unsigned int* ps = &Ps[wid][0];
#pragma unroll
            for (int st = 0; st < 2; ++st) {
                unsigned int v0 = __builtin_bit_cast(unsigned int,
                    __builtin_amdgcn_cvt_pkrtz(p[st][0], p[st][1]));
                unsigned int v1 = __builtin_bit_cast(unsigned int,
                    __builtin_amdgcn_cvt_pkrtz(p[st][2], p[st][3]));
                ps[cl * PLD32 + st * 8 + gq * 2]     = v0;
                ps[cl * PLD32 + st * 8 + gq * 2 + 1] = v1;
            }
            f16x8 pf = *(const f16x8*)(const void*)(ps + cl * PLD32 + gq * 4);
#pragma unroll
            for (int n = 0; n < 8; ++n) {
                int d = n * 16 + cl;
                int slot = d * 4 + (gq ^ ((d >> 1) & 3));
                f16x8 vf = *(const f16x8*)(const void*)(Vb[cur] + slot * 8);
                acc[n] = __builtin_amdgcn_mfma_f32_16x16x32_f16(pf, vf, acc[n], 0, 0, 0);
            }
        }
        __syncthreads();
        cur ^= 1;
    }
#undef STAGE_T
    unsigned char* cq = ctxq + cqbase;
#pragma unroll
    for (int r = 0; r < 4; ++r) {
        int trow = qrow_lo + rb4 + r;
        float inv = 1.0f / __shfl(lrun, rb4 + r);
        float vals[8];
        float am = 0.f;
#pragma unroll
        for (int n = 0; n < 8; ++n) {
            vals[n] = acc[n][r] * inv;
            am = fmaxf(am, fabsf(vals[n]));
        }
#pragma unroll
        for (int o = 8; o; o >>= 1) am = fmaxf(am, __shfl_xor(am, o));
        float s = fmaxf(am / 57344.0f, 1e-12f);
#pragma unroll
        for (int n = 0; n < 8; ++n)
            cq[(size_t)trow * Cdim + n * 16 + cl] = q8_byte(vals[n] / s);
        if (cl == 0) Sc[((size_t)b * Tdim + trow) * NKB + h] = s;
    }
}

// ---------- launch ----------
extern "C" void kernel_launch(void* const* d_in, const int* in_sizes, int n_in,
                              void* d_out, int out_size, void* d_ws, size_t ws_size,
                              hipStream_t stream) {
    const float* x  = (const float*)d_in[0];
    const float* wq = (const float*)d_in[2];
    const float* wk = (const float*)d_in[3];
    const float* wv = (const float*)d_in[4];
    const float* wo = (const float*)d_in[5];
    const float* sq = (const float*)d_in[6];
    const float* sk = (const float*)d_in[7];
    const float* sv = (const float*)d_in[8];
    const float* so = (const float*)d_in[9];

    const size_t MB = 1ull << 20;
    char* ws = (char*)d_ws;
    unsigned char*  xq   = (unsigned char*)(ws);                           // 8MB
    float*          Sx   = (float*)(ws + 8 * MB);                          // 256KB
    float*          Scx  = (float*)(ws + (8 * MB + 256 * 1024));           // 256KB
    unsigned char*  wdq4 = (unsigned char*)(ws + (8 * MB + 512 * 1024));   // 16MB (q|k|v|o)
    unsigned short* OQK  = (unsigned short*)(ws + (24 * MB + 512 * 1024)); // 32MB fp16 q|k
    unsigned short* vt   = (unsigned short*)(ws + (56 * MB + 512 * 1024)); // 16MB fp16 V^T
    unsigned char*  cq   = (unsigned char*)(ws + (72 * MB + 512 * 1024));  // 8MB

    const int Mr = Bdim * Tdim;

    quant_all_k<<<32768, 256, 0, stream>>>(x, wq, wk, wv, wo, xq, Sx, wdq4);

    dim3 gq3(3 * Cdim / 128, Mr / 128);          // (48, 32) = 1536 blocks
    gemm_qkv_k<<<gq3, 256, 0, stream>>>(xq, Sx, wdq4, sq, sk, sv, OQK, vt);

    attn_k<<<1024, 256, 0, stream>>>(OQK, OQK + 2048, vt, cq, Scx);

    dim3 gg(Cdim / 128, Mr / 64);                // (16, 64) = 1024 blocks
    gemm_k<<<gg, 256, 0, stream>>>(cq, Scx, wdq4 + (6144ull * 2048), so,
                                   (float*)d_out, Mr, Cdim, Cdim);
}